// Round 1
// baseline (5981.867 us; speedup 1.0000x reference)
//
#include <hip/hip_runtime.h>
#include <math.h>

#define BT 16          // samples per block
#define NBLK (8192/BT) // 512 blocks

__device__ __forceinline__ float sigf(float x){ return 1.f/(1.f+expf(-x)); }
__device__ __forceinline__ float lrelu(float x){ return (x>0.f)? x : 0.01f*x; }

__device__ __forceinline__ void fma16(float* acc, float w, const float4& a, const float4& b,
                                      const float4& c, const float4& d){
  acc[0]+=w*a.x;  acc[1]+=w*a.y;  acc[2]+=w*a.z;  acc[3]+=w*a.w;
  acc[4]+=w*b.x;  acc[5]+=w*b.y;  acc[6]+=w*b.z;  acc[7]+=w*b.w;
  acc[8]+=w*c.x;  acc[9]+=w*c.y;  acc[10]+=w*c.z; acc[11]+=w*c.w;
  acc[12]+=w*d.x; acc[13]+=w*d.y; acc[14]+=w*d.z; acc[15]+=w*d.w;
}
__device__ __forceinline__ void fma8(float* acc, float w, const float4& a, const float4& b){
  acc[0]+=w*a.x; acc[1]+=w*a.y; acc[2]+=w*a.z; acc[3]+=w*a.w;
  acc[4]+=w*b.x; acc[5]+=w*b.y; acc[6]+=w*b.z; acc[7]+=w*b.w;
}

// acc0/acc1 (16 samples each) += W[g0,:128] . hT  and  W[g1,:128] . hT
__device__ __forceinline__ void gemm2(const float* __restrict__ W, int g0, int g1,
                                      const float (*hT)[16], float* acc0, float* acc1){
  const float4* wr0 = reinterpret_cast<const float4*>(W + g0*128);
  const float4* wr1 = reinterpret_cast<const float4*>(W + g1*128);
  #pragma unroll 2
  for(int k4=0;k4<32;++k4){
    float4 wa4 = wr0[k4];
    float4 wb4 = wr1[k4];
    float wae[4]={wa4.x,wa4.y,wa4.z,wa4.w};
    float wbe[4]={wb4.x,wb4.y,wb4.z,wb4.w};
    #pragma unroll
    for(int e=0;e<4;++e){
      int k=k4*4+e;
      const float4* hp=reinterpret_cast<const float4*>(&hT[k][0]);
      float4 ha=hp[0],hb=hp[1],hc=hp[2],hd=hp[3];
      fma16(acc0,wae[e],ha,hb,hc,hd);
      fma16(acc1,wbe[e],ha,hb,hc,hd);
    }
  }
}

union SMem {
  struct {              // aux phases
    float tfT[128][16];   // text chunk, transposed
    float h256T[256][16]; // tp1 out
    float tpT[128][16];   // tp2 out
    float featT[64][16];  // fft features
    float qk[16][64];
    float v[16][64];
    float adj[16][64];
    float midT[128][16];  // gate mid
  } a;
  struct {              // lstm phases
    float h0T[128][16];
    float h1T[128][16];
    float gpre[16][512];
    float midT[128][16];  // fc1 out (decoder)
  } b;
};

__global__ __launch_bounds__(256,2) void mkty_fused(
    const float* __restrict__ data, const float* __restrict__ text_feature,
    const float* __restrict__ q_w, const float* __restrict__ q_b,
    const float* __restrict__ k_w, const float* __restrict__ k_b,
    const float* __restrict__ v_w, const float* __restrict__ v_b,
    const float* __restrict__ tp1_w, const float* __restrict__ tp1_b,
    const float* __restrict__ tp2_w, const float* __restrict__ tp2_b,
    const float* __restrict__ g1_w, const float* __restrict__ g1_b,
    const float* __restrict__ g2_w, const float* __restrict__ g2_b,
    const float* __restrict__ w_ih0, const float* __restrict__ b_ih0,
    const float* __restrict__ w_hh0, const float* __restrict__ b_hh0,
    const float* __restrict__ w_ih1, const float* __restrict__ b_ih1,
    const float* __restrict__ w_hh1, const float* __restrict__ b_hh1,
    const float* __restrict__ fc1_w, const float* __restrict__ fc1_b,
    const float* __restrict__ fc2_w, const float* __restrict__ fc2_b,
    float* __restrict__ out)
{
  __shared__ SMem sm;
  __shared__ float s_x[16][64];     // data tile (also DFT input)
  __shared__ float s_gate[16][16];
  __shared__ float s_rec[16][16];
  __shared__ float s_res[16][16];
  __shared__ float s_pred[16];
  __shared__ float ctab[64], stab[64];

  const int tid = threadIdx.x;
  const int s0  = blockIdx.x * BT;

  // ---- stage data tile + twiddle tables ----
  {
    int f=tid*4, s=f>>6, j=f&63;
    *reinterpret_cast<float4*>(&s_x[s][j]) =
      *reinterpret_cast<const float4*>(data + (s0+s)*64 + j);
  }
  if (tid<64){
    float sv,cv;
    sincosf((float)tid * 0.09817477042468103f, &sv, &cv); // 2*pi/64
    stab[tid] = (tid==32) ? 0.f : sv;  // exact Nyquist
    ctab[tid] = cv;
  }
  __syncthreads();

  // ================= AUX BRANCH =================
  // Phase A: h256 = leaky(tf @ tp1_w.T + b1)  -- each thread = one of 256 outputs
  {
    float accA[16];
    #pragma unroll
    for(int s=0;s<16;++s) accA[s]=0.f;
    const float4* w1r = reinterpret_cast<const float4*>(tp1_w + tid*1024);
    for(int kc=0;kc<1024;kc+=128){
      __syncthreads();
      { // stage transposed chunk
        int s = tid>>4, j0=(tid&15)*8;
        const float* gp = text_feature + (s0+s)*1024 + kc + j0;
        float4 aa=*reinterpret_cast<const float4*>(gp);
        float4 bb=*reinterpret_cast<const float4*>(gp+4);
        sm.a.tfT[j0+0][s]=aa.x; sm.a.tfT[j0+1][s]=aa.y; sm.a.tfT[j0+2][s]=aa.z; sm.a.tfT[j0+3][s]=aa.w;
        sm.a.tfT[j0+4][s]=bb.x; sm.a.tfT[j0+5][s]=bb.y; sm.a.tfT[j0+6][s]=bb.z; sm.a.tfT[j0+7][s]=bb.w;
      }
      __syncthreads();
      #pragma unroll 2
      for(int k4=0;k4<32;++k4){
        float4 w4 = w1r[(kc>>2)+k4];
        float we[4]={w4.x,w4.y,w4.z,w4.w};
        #pragma unroll
        for(int e=0;e<4;++e){
          int k=k4*4+e;
          const float4* hp=reinterpret_cast<const float4*>(&sm.a.tfT[k][0]);
          float4 ha=hp[0],hb=hp[1],hc=hp[2],hd=hp[3];
          fma16(accA,we[e],ha,hb,hc,hd);
        }
      }
    }
    __syncthreads();
    float bb=tp1_b[tid];
    #pragma unroll
    for(int s=0;s<16;++s) sm.a.h256T[tid][s] = lrelu(accA[s]+bb);
  }
  __syncthreads();

  // Phase B: tp = h256 @ tp2_w.T + b2   (128 outputs x 16 samples)
  {
    const int o2=tid&127, sh=tid>>7;
    float acc8[8];
    #pragma unroll
    for(int i=0;i<8;++i) acc8[i]=0.f;
    const float4* w2r=reinterpret_cast<const float4*>(tp2_w+o2*256);
    #pragma unroll 2
    for(int k4=0;k4<64;++k4){
      float4 w4=w2r[k4];
      float we[4]={w4.x,w4.y,w4.z,w4.w};
      #pragma unroll
      for(int e=0;e<4;++e){
        int k=k4*4+e;
        const float4* hp=reinterpret_cast<const float4*>(&sm.a.h256T[k][sh*8]);
        float4 ha=hp[0],hb=hp[1];
        fma8(acc8,we[e],ha,hb);
      }
    }
    float bb=tp2_b[o2];
    #pragma unroll
    for(int i=0;i<8;++i) sm.a.tpT[o2][sh*8+i]=acc8[i]+bb;
  }
  __syncthreads();

  // Phase C: DFT -> feat = [amp[1..32], phase[1..32]]
  {
    #pragma unroll
    for(int i=0;i<2;++i){
      int task=tid*2+i;
      int s=task>>5;
      int k=(task&31)+1;
      float re=0.f, im=0.f;
      #pragma unroll 8
      for(int n=0;n<64;++n){
        float d=s_x[s][n];
        int m=(k*n)&63;
        re += d*ctab[m];
        im -= d*stab[m];
      }
      if(k==32) im=0.f;
      float amp=sqrtf(re*re+im*im);
      float ph=atan2f(im,re);
      sm.a.featT[k-1][s]=amp;
      sm.a.featT[31+k][s]=ph;
    }
  }
  __syncthreads();

  // Phase D: Q,K,V ; qk = Q*K
  {
    #pragma unroll
    for(int i=0;i<4;++i){
      int task=tid+256*i;
      int s=task>>6, o=task&63;
      float q=q_b[o];
      const float* qwr=q_w+o*64;
      #pragma unroll 4
      for(int k=0;k<64;++k) q+=qwr[k]*sm.a.featT[k][s];
      float kk=k_b[o];
      const float* kwr=k_w+o*128;
      #pragma unroll 4
      for(int k=0;k<128;++k) kk+=kwr[k]*sm.a.tpT[k][s];
      float vv=v_b[o];
      const float* vwr=v_w+o*128;
      #pragma unroll 4
      for(int k=0;k<128;++k) vv+=vwr[k]*sm.a.tpT[k][s];
      sm.a.qk[s][o]=q*kk;
      sm.a.v[s][o]=vv;
    }
  }
  __syncthreads();

  // Phase E: adj = softmax(qk)*v  (serial per sample, 16 threads)
  if(tid<16){
    float m=-1e30f;
    for(int o=0;o<64;++o) m=fmaxf(m,sm.a.qk[tid][o]);
    float sum=0.f;
    for(int o=0;o<64;++o){ float e=expf(sm.a.qk[tid][o]-m); sm.a.adj[tid][o]=e; sum+=e; }
    float inv=1.f/sum;
    for(int o=0;o<64;++o) sm.a.adj[tid][o]=sm.a.adj[tid][o]*inv*sm.a.v[tid][o];
  }
  __syncthreads();

  // Phase F: mid = leaky(adj @ g1_w.T + g1_b)
  {
    int j=tid&127, sh=tid>>7;
    float accm[8];
    float bb=g1_b[j];
    #pragma unroll
    for(int i=0;i<8;++i) accm[i]=bb;
    const float* wr=g1_w+j*64;
    #pragma unroll 4
    for(int k=0;k<64;++k){
      float w=wr[k];
      #pragma unroll
      for(int i=0;i<8;++i) accm[i]+=w*sm.a.adj[sh*8+i][k];
    }
    #pragma unroll
    for(int i=0;i<8;++i) sm.a.midT[j][sh*8+i]=lrelu(accm[i]);
  }
  __syncthreads();

  // Phase G: gate16 + recon16
  {
    int s=tid>>4, o=tid&15;
    float acc=g2_b[o];
    const float* wr=g2_w+o*128;
    #pragma unroll 4
    for(int k=0;k<128;++k) acc+=wr[k]*sm.a.midT[k][s];
    float gate=sigf(acc);
    float sum=0.f;
    float a32=sm.a.adj[s][31];
    float p32=sm.a.adj[s][63];
    #pragma unroll
    for(int k=1;k<32;++k){
      float amp=sm.a.adj[s][k-1];
      float ph =sm.a.adj[s][31+k];
      int m=(k*o)&63;
      sum+=amp*cosf(ph + (float)m*0.09817477042468103f);
    }
    float parity=(o&1)?-1.f:1.f;
    float rec=(2.f*sum + parity*a32*cosf(p32))*(1.f/64.f);
    s_gate[s][o]=gate;
    s_rec[s][o]=rec;
  }
  __syncthreads();

  // ================= LSTM =================
  #pragma unroll
  for(int i=0;i<8;++i){
    int idx=tid+i*256;
    (&sm.b.h0T[0][0])[idx]=0.f;
    (&sm.b.h1T[0][0])[idx]=0.f;
  }
  if(tid<16) s_pred[tid]=s_x[tid][63];
  float c0r[8], c1r[8];
  #pragma unroll
  for(int i=0;i<8;++i){ c0r[i]=0.f; c1r[i]=0.f; }

  const int g0=tid, g1=tid+256;
  const float bias0a=b_ih0[g0]+b_hh0[g0];
  const float bias0b=b_ih0[g1]+b_hh0[g1];
  const float wx0a=w_ih0[g0];
  const float wx0b=w_ih0[g1];
  const float bias1a=b_ih1[g0]+b_hh1[g0];
  const float bias1b=b_ih1[g1]+b_hh1[g1];
  const int cu=tid&127, csh=tid>>7;
  __syncthreads();

  for(int t=0;t<80;++t){
    float acc0[16], acc1[16];
    // GEMM0: w_hh0 . h0 (+ x part + biases)
    #pragma unroll
    for(int s=0;s<16;++s){
      float xv=(t<64)? s_x[s][t] : s_pred[s];
      acc0[s]=bias0a+wx0a*xv;
      acc1[s]=bias0b+wx0b*xv;
    }
    gemm2(w_hh0,g0,g1,sm.b.h0T,acc0,acc1);
    #pragma unroll
    for(int s=0;s<16;++s){ sm.b.gpre[s][g0]=acc0[s]; sm.b.gpre[s][g1]=acc1[s]; }
    __syncthreads();
    // cell0
    #pragma unroll
    for(int i=0;i<8;++i){
      int s=csh*8+i;
      float ig=sm.b.gpre[s][cu];
      float fg=sm.b.gpre[s][cu+128];
      float gg=sm.b.gpre[s][cu+256];
      float og=sm.b.gpre[s][cu+384];
      float c=sigf(fg)*c0r[i]+sigf(ig)*tanhf(gg);
      float h=sigf(og)*tanhf(c);
      c0r[i]=c;
      sm.b.h0T[cu][s]=h;
    }
    __syncthreads();
    // GEMM1: w_ih1 . h0_new + w_hh1 . h1
    #pragma unroll
    for(int s=0;s<16;++s){ acc0[s]=bias1a; acc1[s]=bias1b; }
    gemm2(w_ih1,g0,g1,sm.b.h0T,acc0,acc1);
    gemm2(w_hh1,g0,g1,sm.b.h1T,acc0,acc1);
    #pragma unroll
    for(int s=0;s<16;++s){ sm.b.gpre[s][g0]=acc0[s]; sm.b.gpre[s][g1]=acc1[s]; }
    __syncthreads();
    // cell1
    #pragma unroll
    for(int i=0;i<8;++i){
      int s=csh*8+i;
      float ig=sm.b.gpre[s][cu];
      float fg=sm.b.gpre[s][cu+128];
      float gg=sm.b.gpre[s][cu+256];
      float og=sm.b.gpre[s][cu+384];
      float c=sigf(fg)*c1r[i]+sigf(ig)*tanhf(gg);
      float h=sigf(og)*tanhf(c);
      c1r[i]=c;
      sm.b.h1T[cu][s]=h;
    }
    __syncthreads();

    if(t>=64){
      // fc1: mid = leaky(h1 @ fc1_w.T + b)
      {
        float am[8];
        float bb=fc1_b[cu];
        #pragma unroll
        for(int i=0;i<8;++i) am[i]=bb;
        const float4* wr=reinterpret_cast<const float4*>(fc1_w+cu*128);
        #pragma unroll 2
        for(int k4=0;k4<32;++k4){
          float4 w4=wr[k4];
          float we[4]={w4.x,w4.y,w4.z,w4.w};
          #pragma unroll
          for(int e=0;e<4;++e){
            int k=k4*4+e;
            const float4* hp=reinterpret_cast<const float4*>(&sm.b.h1T[k][csh*8]);
            float4 ha=hp[0],hb=hp[1];
            fma8(am,we[e],ha,hb);
          }
        }
        #pragma unroll
        for(int i=0;i<8;++i) sm.b.midT[cu][csh*8+i]=lrelu(am[i]);
      }
      __syncthreads();
      // fc2: pred = mid @ fc2_w + b
      {
        int s=tid>>4, p=tid&15;
        float sum=0.f;
        #pragma unroll
        for(int j=0;j<8;++j){
          int jj=p*8+j;
          sum+=fc2_w[jj]*sm.b.midT[jj][s];
        }
        sum+=__shfl_xor(sum,1,16);
        sum+=__shfl_xor(sum,2,16);
        sum+=__shfl_xor(sum,4,16);
        sum+=__shfl_xor(sum,8,16);
        if(p==0){
          float pred=sum+fc2_b[0];
          s_pred[s]=pred;
          s_res[s][t-64]=pred;
        }
      }
      __syncthreads();
    }
  }

  // ---- final combine ----
  {
    int s=tid>>4, d=tid&15;
    float g=s_gate[s][d];
    float r=s_res[s][d];
    float rec=s_rec[s][d];
    out[blockIdx.x*256+tid]=g*r+(1.f-g)*rec;
  }
}

extern "C" void kernel_launch(void* const* d_in, const int* in_sizes, int n_in,
                              void* d_out, int out_size, void* d_ws, size_t ws_size,
                              hipStream_t stream){
  const float* data =(const float*)d_in[0];
  const float* tf   =(const float*)d_in[1];
  const float* q_w  =(const float*)d_in[2];  const float* q_b  =(const float*)d_in[3];
  const float* k_w  =(const float*)d_in[4];  const float* k_b  =(const float*)d_in[5];
  const float* v_w  =(const float*)d_in[6];  const float* v_b  =(const float*)d_in[7];
  const float* tp1_w=(const float*)d_in[8];  const float* tp1_b=(const float*)d_in[9];
  const float* tp2_w=(const float*)d_in[10]; const float* tp2_b=(const float*)d_in[11];
  const float* g1_w =(const float*)d_in[12]; const float* g1_b =(const float*)d_in[13];
  const float* g2_w =(const float*)d_in[14]; const float* g2_b =(const float*)d_in[15];
  const float* w_ih0=(const float*)d_in[16]; const float* b_ih0=(const float*)d_in[17];
  const float* w_hh0=(const float*)d_in[18]; const float* b_hh0=(const float*)d_in[19];
  const float* w_ih1=(const float*)d_in[20]; const float* b_ih1=(const float*)d_in[21];
  const float* w_hh1=(const float*)d_in[22]; const float* b_hh1=(const float*)d_in[23];
  const float* fc1_w=(const float*)d_in[24]; const float* fc1_b=(const float*)d_in[25];
  const float* fc2_w=(const float*)d_in[26]; const float* fc2_b=(const float*)d_in[27];
  float* out=(float*)d_out;
  mkty_fused<<<NBLK,256,0,stream>>>(data,tf,q_w,q_b,k_w,k_b,v_w,v_b,
                                    tp1_w,tp1_b,tp2_w,tp2_b,g1_w,g1_b,g2_w,g2_b,
                                    w_ih0,b_ih0,w_hh0,b_hh0,w_ih1,b_ih1,w_hh1,b_hh1,
                                    fc1_w,fc1_b,fc2_w,fc2_b,out);
}

// Round 2
// 2480.705 us; speedup vs baseline: 2.4114x; 2.4114x over previous
//
#include <hip/hip_runtime.h>
#include <hip/hip_fp16.h>
#include <math.h>

typedef _Float16 half8 __attribute__((ext_vector_type(8)));
typedef float f32x4 __attribute__((ext_vector_type(4)));

#define W0F 0.09817477042468103f   // 2*pi/64

__device__ __forceinline__ float sigf(float x){ return 1.f/(1.f+expf(-x)); }
__device__ __forceinline__ float lrelu(float x){ return (x>0.f)? x : 0.01f*x; }

// pack float -> (hi f16 in low16, lo f16 in high16)
__device__ __forceinline__ uint32_t packhl(float x){
  __half h = __float2half(x);
  __half l = __float2half(x - __half2float(h));
  return (uint32_t)__half_as_ushort(h) | ((uint32_t)__half_as_ushort(l) << 16);
}

// 8 packed dwords (two uint4) -> hi-frag and lo-frag (half8)
__device__ __forceinline__ void unpackA(const uint4 d0, const uint4 d1, half8& hi, half8& lo){
  union { half8 h; uint32_t u[4]; } H, L;
  H.u[0] = (d0.x & 0xffffu) | (d0.y << 16);
  H.u[1] = (d0.z & 0xffffu) | (d0.w << 16);
  H.u[2] = (d1.x & 0xffffu) | (d1.y << 16);
  H.u[3] = (d1.z & 0xffffu) | (d1.w << 16);
  L.u[0] = (d0.x >> 16) | (d0.y & 0xffff0000u);
  L.u[1] = (d0.z >> 16) | (d0.w & 0xffff0000u);
  L.u[2] = (d1.x >> 16) | (d1.y & 0xffff0000u);
  L.u[3] = (d1.z >> 16) | (d1.w & 0xffff0000u);
  hi = H.h; lo = L.h;
}

// split-f16 3-pass fp32-accurate MFMA
__device__ __forceinline__ f32x4 mfma3(half8 ah, half8 al, half8 bh, half8 bl, f32x4 c){
  c = __builtin_amdgcn_mfma_f32_16x16x32_f16(ah, bh, c, 0,0,0);
  c = __builtin_amdgcn_mfma_f32_16x16x32_f16(al, bh, c, 0,0,0);
  c = __builtin_amdgcn_mfma_f32_16x16x32_f16(ah, bl, c, 0,0,0);
  return c;
}

// ---- ws layout (halves) ----
// WH0 hi@0 lo@65536 ; WI1 hi@131072 lo@196608 ; WH1 hi@262144 lo@327680
// FC1 hi@393216 lo@409600 ; TP1 hi@425984 lo@688128 ; total 950272 halves (1.86MB)
__global__ __launch_bounds__(256) void convert_w(
    const float* __restrict__ w_hh0, const float* __restrict__ w_ih1,
    const float* __restrict__ w_hh1, const float* __restrict__ fc1_w,
    const float* __restrict__ tp1_w, __half* __restrict__ wsH)
{
  int c = blockIdx.x*256 + threadIdx.x;   // 59392 chunks of 8 elems
  const float* src; size_t dhi, dlo; int n, k, K;
  if (c < 24576){
    int m = c >> 13; int q = c & 8191;
    src = (m==0)? w_hh0 : ((m==1)? w_ih1 : w_hh1); K = 128;
    dhi = (size_t)m*131072 + (size_t)q*8; dlo = dhi + 65536;
    int tile = q >> 8, ks = (q >> 6) & 3, lane = q & 63;
    n = tile*16 + (lane & 15); k = ks*32 + (lane >> 4)*8;
  } else if (c < 26624){
    int q = c - 24576; src = fc1_w; K = 128;
    dhi = 393216 + (size_t)q*8; dlo = 409600 + (size_t)q*8;
    int tile = q >> 8, ks = (q >> 6) & 3, lane = q & 63;
    n = tile*16 + (lane & 15); k = ks*32 + (lane >> 4)*8;
  } else {
    int q = c - 26624; src = tp1_w; K = 1024;
    dhi = 425984 + (size_t)q*8; dlo = 688128 + (size_t)q*8;
    int tile = q >> 11, ks = (q >> 6) & 31, lane = q & 63;
    n = tile*16 + (lane & 15); k = ks*32 + (lane >> 4)*8;
  }
  float4 a = *(const float4*)(src + (size_t)n*K + k);
  float4 b = *(const float4*)(src + (size_t)n*K + k + 4);
  float vv[8] = {a.x,a.y,a.z,a.w,b.x,b.y,b.z,b.w};
  union { uint4 u; unsigned short s[8]; } HI, LO;
  #pragma unroll
  for (int j = 0; j < 8; ++j){
    __half hh = __float2half(vv[j]);
    __half ll = __float2half(vv[j] - __half2float(hh));
    HI.s[j] = __half_as_ushort(hh);
    LO.s[j] = __half_as_ushort(ll);
  }
  *(uint4*)(wsH + dhi) = HI.u;
  *(uint4*)(wsH + dlo) = LO.u;
}

__global__ __launch_bounds__(512,2) void mkty_main(
    const float* __restrict__ data, const float* __restrict__ text_feature,
    const float* __restrict__ q_w, const float* __restrict__ q_b,
    const float* __restrict__ k_w, const float* __restrict__ k_b,
    const float* __restrict__ v_w, const float* __restrict__ v_b,
    const float* __restrict__ tp1_b,
    const float* __restrict__ tp2_w, const float* __restrict__ tp2_b,
    const float* __restrict__ g1_w, const float* __restrict__ g1_b,
    const float* __restrict__ g2_w, const float* __restrict__ g2_b,
    const float* __restrict__ w_ih0, const float* __restrict__ b_ih0,
    const float* __restrict__ b_hh0,
    const float* __restrict__ b_ih1, const float* __restrict__ b_hh1,
    const float* __restrict__ fc1_b,
    const float* __restrict__ fc2_w, const float* __restrict__ fc2_b,
    const __half* __restrict__ wsH, float* __restrict__ out)
{
  __shared__ float s_x[32][64];          // 8K
  __shared__ float s_gate[32][16];       // 2K
  __shared__ float s_rec[32][16];        // 2K
  __shared__ float s_res[32][16];        // 2K
  __shared__ float s_pred[32];
  __shared__ float ctab[64], stab[64];
  __shared__ __align__(16) unsigned char bufBig[33792]; // h256[32][260] | featT/QK/V | h0p+h1p [32][132] dwords x2
  __shared__ __align__(16) unsigned char bufMed[16384]; // tfp[32][68] dw | tpT[32][128] | midT[32][128] | midD[32][128]

  const int tid = threadIdx.x;
  const int w = tid >> 6, l = tid & 63;
  const int lm = l & 15, lq = l >> 4;
  const int s0blk = blockIdx.x * 32;

  { int s = tid >> 4, j = (tid*4) & 63;
    *(float4*)&s_x[s][j] = *(const float4*)(data + (size_t)(s0blk+s)*64 + j); }
  if (tid < 64){ float sv,cv; sincosf((float)tid*W0F,&sv,&cv);
    stab[tid] = (tid==32)?0.f:sv; ctab[tid]=cv; }
  __syncthreads();

  // ================= Phase A: h256 = lrelu(tf @ tp1_w^T + b1)  (MFMA) =================
  {
    float* h256 = (float*)bufBig;            // [32][260]
    uint32_t* tfp = (uint32_t*)bufMed;       // [32][68] packed hi/lo
    const half8* T1h = (const half8*)(wsH + 425984);
    const half8* T1l = (const half8*)(wsH + 688128);
    const int t0 = 2*w;
    f32x4 acc[2][2];
    #pragma unroll
    for (int mt=0; mt<2; ++mt)
      #pragma unroll
      for (int nt=0; nt<2; ++nt){ f32x4 z = {0.f,0.f,0.f,0.f}; acc[mt][nt] = z; }
    for (int kc = 0; kc < 1024; kc += 64){
      __syncthreads();
      { int s = tid >> 4, j0 = (tid & 15)*4;
        float4 v = *(const float4*)(text_feature + (size_t)(s0blk+s)*1024 + kc + j0);
        uint4 p; p.x = packhl(v.x); p.y = packhl(v.y); p.z = packhl(v.z); p.w = packhl(v.w);
        *(uint4*)&tfp[s*68 + j0] = p; }
      __syncthreads();
      #pragma unroll
      for (int ks = 0; ks < 2; ++ks){
        half8 Ah[2], Al[2];
        #pragma unroll
        for (int mt = 0; mt < 2; ++mt){
          const uint32_t* pp = &tfp[(mt*16+lm)*68 + ks*32 + lq*8];
          unpackA(*(const uint4*)pp, *(const uint4*)(pp+4), Ah[mt], Al[mt]);
        }
        int ksg = (kc >> 5) + ks;
        #pragma unroll
        for (int nt = 0; nt < 2; ++nt){
          int ci = ((t0+nt)*32 + ksg)*64 + l;
          half8 bh = T1h[ci], bl = T1l[ci];
          #pragma unroll
          for (int mt = 0; mt < 2; ++mt)
            acc[mt][nt] = mfma3(Ah[mt],Al[mt],bh,bl,acc[mt][nt]);
        }
      }
    }
    #pragma unroll
    for (int nt = 0; nt < 2; ++nt){
      int n = (t0+nt)*16 + lm;
      float bb = tp1_b[n];
      #pragma unroll
      for (int mt = 0; mt < 2; ++mt)
        #pragma unroll
        for (int r = 0; r < 4; ++r)
          h256[(mt*16 + lq*4 + r)*260 + n] = lrelu(acc[mt][nt][r] + bb);
    }
  }
  __syncthreads();

  // ================= Phase B: tp = h256 @ tp2_w^T + b2  (VALU k-major) =================
  {
    const float* h256 = (const float*)bufBig;
    int o = tid & 127, soct = tid >> 7, ss = soct*8;
    float acc8[8];
    #pragma unroll
    for (int i=0;i<8;++i) acc8[i]=0.f;
    const float4* w2r = (const float4*)(tp2_w + o*256);
    #pragma unroll 4
    for (int k4 = 0; k4 < 64; ++k4){
      float4 w4 = w2r[k4];
      #pragma unroll
      for (int i = 0; i < 8; ++i){
        float4 hv = *(const float4*)&h256[(ss+i)*260 + k4*4];
        acc8[i] += w4.x*hv.x; acc8[i] += w4.y*hv.y;
        acc8[i] += w4.z*hv.z; acc8[i] += w4.w*hv.w;
      }
    }
    __syncthreads();                 // all h256 reads done before tpT overwrites tfp region? (different buf) + before C overwrites h256
    float* tpT = (float*)bufMed;     // [32][128]
    float bb = tp2_b[o];
    #pragma unroll
    for (int i=0;i<8;++i) tpT[(ss+i)*128 + o] = acc8[i] + bb;
  }
  __syncthreads();

  // ================= Phase C: DFT -> featT[64][32] =================
  {
    float* featT = (float*)bufBig;
    #pragma unroll
    for (int i = 0; i < 2; ++i){
      int task = tid + 512*i;
      int s = task >> 5;
      int k = (task & 31) + 1;
      float re = 0.f, im = 0.f;
      #pragma unroll 8
      for (int n = 0; n < 64; ++n){
        float d = s_x[s][n];
        int m = (k*n) & 63;
        re += d*ctab[m]; im -= d*stab[m];
      }
      if (k == 32) im = 0.f;
      featT[(k-1)*32 + s] = sqrtf(re*re + im*im);
      featT[(31+k)*32 + s] = atan2f(im, re);
    }
  }
  __syncthreads();

  // ================= Phase D: Q,K,V ; QK = Q*K =================
  {
    const float* featT = (const float*)bufBig;
    const float* tpT = (const float*)bufMed;
    float* QK = (float*)(bufBig + 8192);
    float* V  = (float*)(bufBig + 16384);
    #pragma unroll
    for (int i = 0; i < 4; ++i){
      int task = tid + 512*i;
      int s = task >> 6, o = task & 63;
      float q = q_b[o];
      const float* qwr = q_w + o*64;
      #pragma unroll 4
      for (int k = 0; k < 64; ++k) q += qwr[k]*featT[k*32 + s];
      float kk = k_b[o];
      const float* kwr = k_w + o*128;
      const float* tps = tpT + s*128;
      #pragma unroll 4
      for (int k = 0; k < 128; ++k) kk += kwr[k]*tps[k];
      float vv = v_b[o];
      const float* vwr = v_w + o*128;
      #pragma unroll 4
      for (int k = 0; k < 128; ++k) vv += vwr[k]*tps[k];
      QK[s*64+o] = q*kk; V[s*64+o] = vv;
    }
  }
  __syncthreads();

  // ================= Phase E: adj = softmax(QK)*V (in-place in QK) =================
  if (tid < 32){
    float* QK = (float*)(bufBig + 8192);
    const float* V = (const float*)(bufBig + 16384);
    float mx = -1e30f;
    for (int o = 0; o < 64; ++o) mx = fmaxf(mx, QK[tid*64+o]);
    float sum = 0.f;
    for (int o = 0; o < 64; ++o){ float e = expf(QK[tid*64+o]-mx); QK[tid*64+o] = e; sum += e; }
    float inv = 1.f/sum;
    for (int o = 0; o < 64; ++o) QK[tid*64+o] *= inv*V[tid*64+o];
  }
  __syncthreads();

  // ================= Phase F: mid = lrelu(adj @ g1_w^T + b) =================
  {
    const float* ADJ = (const float*)(bufBig + 8192);
    float* midT = (float*)bufMed;    // [32][128]
    int j = tid & 127, soct = tid >> 7, ss = soct*8;
    float accm[8];
    float bb = g1_b[j];
    #pragma unroll
    for (int i=0;i<8;++i) accm[i]=bb;
    const float* wr = g1_w + j*64;
    #pragma unroll 4
    for (int k = 0; k < 64; ++k){
      float ww = wr[k];
      #pragma unroll
      for (int i=0;i<8;++i) accm[i] += ww*ADJ[(ss+i)*64 + k];
    }
    #pragma unroll
    for (int i=0;i<8;++i) midT[(ss+i)*128 + j] = lrelu(accm[i]);
  }
  __syncthreads();

  // ================= Phase G: gate + recon =================
  {
    int s = tid >> 4, o = tid & 15;
    const float* midT = (const float*)bufMed;
    const float* ADJ = (const float*)(bufBig + 8192);
    float acc = g2_b[o];
    const float* wr = g2_w + o*128;
    #pragma unroll 4
    for (int k = 0; k < 128; ++k) acc += wr[k]*midT[s*128 + k];
    float gate = sigf(acc);
    float sum = 0.f;
    float a32 = ADJ[s*64+31], p32 = ADJ[s*64+63];
    #pragma unroll
    for (int k = 1; k < 32; ++k){
      float amp = ADJ[s*64 + k-1];
      float ph  = ADJ[s*64 + 31+k];
      int m = (k*o) & 63;
      sum += amp*cosf(ph + (float)m*W0F);
    }
    float parity = (o&1)? -1.f : 1.f;
    s_gate[s][o] = gate;
    s_rec[s][o] = (2.f*sum + parity*a32*cosf(p32))*(1.f/64.f);
  }
  __syncthreads();

  // ================= LSTM (split-f16 MFMA) =================
  { uint32_t* hp = (uint32_t*)bufBig;
    for (int i = tid; i < 8448; i += 512) hp[i] = 0; }
  if (tid < 32) s_pred[tid] = s_x[tid][63];

  float c0[2][4] = {{0.f,0.f,0.f,0.f},{0.f,0.f,0.f,0.f}};
  float c1[2][4] = {{0.f,0.f,0.f,0.f},{0.f,0.f,0.f,0.f}};
  const int u = 16*w + lm;
  float bias0[4], wx0[4], bias1[4];
  #pragma unroll
  for (int T = 0; T < 4; ++T){
    int n = T*128 + u;
    bias0[T] = b_ih0[n] + b_hh0[n];
    wx0[T]   = w_ih0[n];
    bias1[T] = b_ih1[n] + b_hh1[n];
  }
  const float fb = fc1_b[u];
  const half8* WH0h = (const half8*)(wsH);
  const half8* WH0l = (const half8*)(wsH + 65536);
  const half8* WI1h = (const half8*)(wsH + 131072);
  const half8* WI1l = (const half8*)(wsH + 196608);
  const half8* WH1h = (const half8*)(wsH + 262144);
  const half8* WH1l = (const half8*)(wsH + 327680);
  const half8* F1h  = (const half8*)(wsH + 393216);
  const half8* F1l  = (const half8*)(wsH + 409600);
  uint32_t* h0p = (uint32_t*)bufBig;             // [32][132]
  uint32_t* h1p = (uint32_t*)(bufBig + 16896);   // [32][132]
  float* midD = (float*)bufMed;                  // [32][128]
  const int cbase = w*256 + l;
  __syncthreads();

  for (int t = 0; t < 80; ++t){
    // ---- GEMM0: gates0 = h0 @ WH0^T + x*w_ih0 + b ----
    float xv[2][4];
    #pragma unroll
    for (int mt = 0; mt < 2; ++mt)
      #pragma unroll
      for (int r = 0; r < 4; ++r){
        int m = mt*16 + lq*4 + r;
        xv[mt][r] = (t < 64) ? s_x[m][t] : s_pred[m];
      }
    f32x4 acc0[2][4];
    #pragma unroll
    for (int nt = 0; nt < 4; ++nt)
      #pragma unroll
      for (int mt = 0; mt < 2; ++mt){
        f32x4 a;
        #pragma unroll
        for (int r = 0; r < 4; ++r) a[r] = bias0[nt] + wx0[nt]*xv[mt][r];
        acc0[mt][nt] = a;
      }
    #pragma unroll
    for (int ks = 0; ks < 4; ++ks){
      half8 Ah[2], Al[2];
      #pragma unroll
      for (int mt = 0; mt < 2; ++mt){
        const uint32_t* pp = &h0p[(mt*16+lm)*132 + ks*32 + lq*8];
        unpackA(*(const uint4*)pp, *(const uint4*)(pp+4), Ah[mt], Al[mt]);
      }
      #pragma unroll
      for (int nt = 0; nt < 4; ++nt){
        int ci = nt*2048 + ks*64 + cbase;
        half8 bh = WH0h[ci], bl = WH0l[ci];
        #pragma unroll
        for (int mt = 0; mt < 2; ++mt)
          acc0[mt][nt] = mfma3(Ah[mt],Al[mt],bh,bl,acc0[mt][nt]);
      }
    }
    __syncthreads();   // S1: all GEMM0 reads of h0p done
    #pragma unroll
    for (int mt = 0; mt < 2; ++mt)
      #pragma unroll
      for (int r = 0; r < 4; ++r){
        float gi = acc0[mt][0][r], gf = acc0[mt][1][r];
        float gg = acc0[mt][2][r], go = acc0[mt][3][r];
        float c = sigf(gf)*c0[mt][r] + sigf(gi)*tanhf(gg);
        float h = sigf(go)*tanhf(c);
        c0[mt][r] = c;
        h0p[(mt*16 + lq*4 + r)*132 + u] = packhl(h);
      }
    __syncthreads();   // S2: new h0 visible
    // ---- GEMM1: gates1 = h0new @ WI1^T + h1 @ WH1^T + b ----
    f32x4 acc1[2][4];
    #pragma unroll
    for (int nt = 0; nt < 4; ++nt)
      #pragma unroll
      for (int mt = 0; mt < 2; ++mt){
        f32x4 a; float bb = bias1[nt];
        a[0]=bb; a[1]=bb; a[2]=bb; a[3]=bb;
        acc1[mt][nt] = a;
      }
    #pragma unroll
    for (int ks = 0; ks < 4; ++ks){
      half8 A0h[2], A0l[2], A1h[2], A1l[2];
      #pragma unroll
      for (int mt = 0; mt < 2; ++mt){
        const uint32_t* p0 = &h0p[(mt*16+lm)*132 + ks*32 + lq*8];
        unpackA(*(const uint4*)p0, *(const uint4*)(p0+4), A0h[mt], A0l[mt]);
        const uint32_t* p1 = &h1p[(mt*16+lm)*132 + ks*32 + lq*8];
        unpackA(*(const uint4*)p1, *(const uint4*)(p1+4), A1h[mt], A1l[mt]);
      }
      #pragma unroll
      for (int nt = 0; nt < 4; ++nt){
        int ci = nt*2048 + ks*64 + cbase;
        half8 bh0 = WI1h[ci], bl0 = WI1l[ci];
        half8 bh1 = WH1h[ci], bl1 = WH1l[ci];
        #pragma unroll
        for (int mt = 0; mt < 2; ++mt){
          acc1[mt][nt] = mfma3(A0h[mt],A0l[mt],bh0,bl0,acc1[mt][nt]);
          acc1[mt][nt] = mfma3(A1h[mt],A1l[mt],bh1,bl1,acc1[mt][nt]);
        }
      }
    }
    __syncthreads();   // S3: GEMM1 reads of h1p done
    #pragma unroll
    for (int mt = 0; mt < 2; ++mt)
      #pragma unroll
      for (int r = 0; r < 4; ++r){
        float gi = acc1[mt][0][r], gf = acc1[mt][1][r];
        float gg = acc1[mt][2][r], go = acc1[mt][3][r];
        float c = sigf(gf)*c1[mt][r] + sigf(gi)*tanhf(gg);
        float h = sigf(go)*tanhf(c);
        c1[mt][r] = c;
        h1p[(mt*16 + lq*4 + r)*132 + u] = packhl(h);
      }
    __syncthreads();   // S4: new h1 visible

    if (t >= 64){
      // fc1: mid = lrelu(h1 @ fc1_w^T + b)
      f32x4 fa[2];
      #pragma unroll
      for (int mt = 0; mt < 2; ++mt){ f32x4 a; a[0]=fb;a[1]=fb;a[2]=fb;a[3]=fb; fa[mt]=a; }
      #pragma unroll
      for (int ks = 0; ks < 4; ++ks){
        half8 Ah[2], Al[2];
        #pragma unroll
        for (int mt = 0; mt < 2; ++mt){
          const uint32_t* pp = &h1p[(mt*16+lm)*132 + ks*32 + lq*8];
          unpackA(*(const uint4*)pp, *(const uint4*)(pp+4), Ah[mt], Al[mt]);
        }
        int ci = (w*4 + ks)*64 + l;
        half8 bh = F1h[ci], bl = F1l[ci];
        #pragma unroll
        for (int mt = 0; mt < 2; ++mt)
          fa[mt] = mfma3(Ah[mt],Al[mt],bh,bl,fa[mt]);
      }
      #pragma unroll
      for (int mt = 0; mt < 2; ++mt)
        #pragma unroll
        for (int r = 0; r < 4; ++r)
          midD[(mt*16 + lq*4 + r)*128 + u] = lrelu(fa[mt][r]);
      __syncthreads(); // S5
      {
        int m = tid >> 4, jg = tid & 15, j0 = jg*8;
        float4 wa = *(const float4*)(fc2_w + j0);
        float4 wb = *(const float4*)(fc2_w + j0 + 4);
        const float* mp = &midD[m*128 + j0];
        float4 ma = *(const float4*)mp, mb = *(const float4*)(mp+4);
        float sum = wa.x*ma.x + wa.y*ma.y + wa.z*ma.z + wa.w*ma.w
                  + wb.x*mb.x + wb.y*mb.y + wb.z*mb.z + wb.w*mb.w;
        sum += __shfl_xor(sum, 1, 16);
        sum += __shfl_xor(sum, 2, 16);
        sum += __shfl_xor(sum, 4, 16);
        sum += __shfl_xor(sum, 8, 16);
        if (jg == 0){
          float pred = sum + fc2_b[0];
          s_pred[m] = pred;
          s_res[m][t-64] = pred;
        }
      }
      __syncthreads(); // S6: s_pred visible for next step
    }
  }

  // ---- final combine ----
  {
    int s = tid >> 4, d = tid & 15;
    float g = s_gate[s][d];
    out[(size_t)blockIdx.x*512 + tid] = g*s_res[s][d] + (1.f - g)*s_rec[s][d];
  }
}

extern "C" void kernel_launch(void* const* d_in, const int* in_sizes, int n_in,
                              void* d_out, int out_size, void* d_ws, size_t ws_size,
                              hipStream_t stream){
  const float* data =(const float*)d_in[0];
  const float* tf   =(const float*)d_in[1];
  const float* q_w  =(const float*)d_in[2];  const float* q_b  =(const float*)d_in[3];
  const float* k_w  =(const float*)d_in[4];  const float* k_b  =(const float*)d_in[5];
  const float* v_w  =(const float*)d_in[6];  const float* v_b  =(const float*)d_in[7];
  const float* tp1_w=(const float*)d_in[8];  const float* tp1_b=(const float*)d_in[9];
  const float* tp2_w=(const float*)d_in[10]; const float* tp2_b=(const float*)d_in[11];
  const float* g1_w =(const float*)d_in[12]; const float* g1_b =(const float*)d_in[13];
  const float* g2_w =(const float*)d_in[14]; const float* g2_b =(const float*)d_in[15];
  const float* w_ih0=(const float*)d_in[16]; const float* b_ih0=(const float*)d_in[17];
  const float* w_hh0=(const float*)d_in[18]; const float* b_hh0=(const float*)d_in[19];
  const float* w_ih1=(const float*)d_in[20]; const float* b_ih1=(const float*)d_in[21];
  const float* w_hh1=(const float*)d_in[22]; const float* b_hh1=(const float*)d_in[23];
  const float* fc1_w=(const float*)d_in[24]; const float* fc1_b=(const float*)d_in[25];
  const float* fc2_w=(const float*)d_in[26]; const float* fc2_b=(const float*)d_in[27];
  float* out=(float*)d_out;
  __half* wsH = (__half*)d_ws;

  convert_w<<<232,256,0,stream>>>(w_hh0, w_ih1, w_hh1, fc1_w, tp1_w, wsH);
  mkty_main<<<256,512,0,stream>>>(data, tf, q_w,q_b, k_w,k_b, v_w,v_b,
                                  tp1_b, tp2_w,tp2_b, g1_w,g1_b, g2_w,g2_b,
                                  w_ih0,b_ih0,b_hh0, b_ih1,b_hh1,
                                  fc1_b, fc2_w,fc2_b, wsH, out);
}